// Round 1
// baseline (1018.864 us; speedup 1.0000x reference)
//
#include <hip/hip_runtime.h>
#include <math.h>

#define N_NODES 30000
#define N_EDGES 240000
#define DMODEL 256
#define NETYPES 8
#define NGRAPHS 64
#define NLAYERS 3

// ---------------- CSR build (by destination node) ----------------
__global__ void k_count_deg(const int* __restrict__ dst, int* __restrict__ deg) {
  int e = blockIdx.x * blockDim.x + threadIdx.x;
  if (e < N_EDGES) atomicAdd(&deg[dst[e]], 1);
}

__global__ __launch_bounds__(1024) void k_scan(const int* __restrict__ deg,
                                               int* __restrict__ rowstart,
                                               int* __restrict__ cursor) {
  __shared__ int buf[1024];
  __shared__ int carry_s;
  int tid = threadIdx.x;
  if (tid == 0) carry_s = 0;
  __syncthreads();
  for (int base = 0; base < N_NODES; base += 1024) {
    int i = base + tid;
    int v = (i < N_NODES) ? deg[i] : 0;
    buf[tid] = v;
    __syncthreads();
    for (int off = 1; off < 1024; off <<= 1) {
      int t2 = (tid >= off) ? buf[tid - off] : 0;
      __syncthreads();
      buf[tid] += t2;
      __syncthreads();
    }
    int incl = buf[tid];
    int carry = carry_s;
    if (i < N_NODES) {
      rowstart[i] = carry + incl - v;
      cursor[i]   = carry + incl - v;
    }
    __syncthreads();
    if (tid == 1023) carry_s = carry + incl;
    __syncthreads();
  }
  if (tid == 0) rowstart[N_NODES] = carry_s;
}

__global__ void k_scatter(const int* __restrict__ dst, int* __restrict__ cursor,
                          int* __restrict__ edgeids) {
  int e = blockIdx.x * blockDim.x + threadIdx.x;
  if (e < N_EDGES) {
    int p = atomicAdd(&cursor[dst[e]], 1);
    edgeids[p] = e;
  }
}

// ---------------- fused QKV GEMM: C[N,768] = A[N,256] @ [Wq|Wk|Wv] + bias ----------
// fp32 vector-ALU SGEMM, 128x128x16 tile, 8x8 per thread.
__global__ __launch_bounds__(256) void k_gemm_qkv(
    const float* __restrict__ A,
    const float* __restrict__ Wq, const float* __restrict__ Wk, const float* __restrict__ Wv,
    const float* __restrict__ bq, const float* __restrict__ bk, const float* __restrict__ bv,
    float* __restrict__ C) {
  __shared__ float As[16][132];   // [kk][m], padded
  __shared__ float Bs[16][128];   // [kk][n]
  int t = threadIdx.x;
  int bm = blockIdx.x, bn = blockIdx.y;      // bn in 0..5 (128-col blocks of 768)
  int which = bn >> 1;                        // 0=q 1=k 2=v
  const float* W    = (which == 0) ? Wq : ((which == 1) ? Wk : Wv);
  const float* bias = (which == 0) ? bq : ((which == 1) ? bk : bv);
  int coloff = (bn & 1) * 128;                // column offset inside the 256-wide W
  int row0 = bm * 128;
  int tx = t & 15, ty = t >> 4;
  int ar = t >> 2, ac4 = t & 3;               // A staging: row=ar(+64), 4 k's at ac4*4
  int bkk = t >> 4, bcol = (t & 15) * 8;      // B staging

  float acc[8][8];
#pragma unroll
  for (int i = 0; i < 8; ++i)
#pragma unroll
    for (int j = 0; j < 8; ++j) acc[i][j] = 0.f;

  for (int k0 = 0; k0 < 256; k0 += 16) {
#pragma unroll
    for (int h = 0; h < 2; ++h) {
      int r = ar + h * 64;
      int grow = row0 + r;
      float4 av = make_float4(0.f, 0.f, 0.f, 0.f);
      if (grow < N_NODES) av = *(const float4*)(A + (size_t)grow * 256 + k0 + ac4 * 4);
      As[ac4 * 4 + 0][r] = av.x;
      As[ac4 * 4 + 1][r] = av.y;
      As[ac4 * 4 + 2][r] = av.z;
      As[ac4 * 4 + 3][r] = av.w;
    }
    const float* wp = W + (size_t)(k0 + bkk) * 256 + coloff + bcol;
    float4 b0 = *(const float4*)wp;
    float4 b1 = *(const float4*)(wp + 4);
    *(float4*)&Bs[bkk][bcol]     = b0;
    *(float4*)&Bs[bkk][bcol + 4] = b1;
    __syncthreads();
#pragma unroll
    for (int kk = 0; kk < 16; ++kk) {
      float af[8], bf[8];
      *(float4*)&af[0] = *(const float4*)&As[kk][ty * 8];
      *(float4*)&af[4] = *(const float4*)&As[kk][ty * 8 + 4];
      *(float4*)&bf[0] = *(const float4*)&Bs[kk][tx * 8];
      *(float4*)&bf[4] = *(const float4*)&Bs[kk][tx * 8 + 4];
#pragma unroll
      for (int i = 0; i < 8; ++i)
#pragma unroll
        for (int j = 0; j < 8; ++j) acc[i][j] = fmaf(af[i], bf[j], acc[i][j]);
    }
    __syncthreads();
  }
  float bj[8];
#pragma unroll
  for (int j = 0; j < 8; ++j) bj[j] = bias[coloff + tx * 8 + j];
#pragma unroll
  for (int i = 0; i < 8; ++i) {
    int grow = row0 + ty * 8 + i;
    if (grow < N_NODES) {
      float* cp = C + (size_t)grow * 768 + bn * 128 + tx * 8;
      float4 o0, o1;
      o0.x = acc[i][0] + bj[0]; o0.y = acc[i][1] + bj[1];
      o0.z = acc[i][2] + bj[2]; o0.w = acc[i][3] + bj[3];
      o1.x = acc[i][4] + bj[4]; o1.y = acc[i][5] + bj[5];
      o1.z = acc[i][6] + bj[6]; o1.w = acc[i][7] + bj[7];
      *(float4*)cp       = o0;
      *(float4*)(cp + 4) = o1;
    }
  }
}

// ---------------- per-dst-node edge attention, online softmax, no atomics ----------
// one wave (64 lanes) per node; lane owns 4 contiguous channels (float4);
// head = lane/16 -> per-head dot via 16-lane xor-shuffle reduce.
__global__ __launch_bounds__(256) void k_attn(
    const float* __restrict__ qkv, const int* __restrict__ rowstart,
    const int* __restrict__ edgeids, const int* __restrict__ src,
    const int* __restrict__ etype, const float* __restrict__ Eemb_l,
    float* __restrict__ xout) {
  __shared__ float ete_s[NETYPES * 256];
  int t = threadIdx.x;
#pragma unroll
  for (int i = 0; i < NETYPES; ++i) ete_s[i * 256 + t] = Eemb_l[i * 256 + t];
  __syncthreads();
  int lane = t & 63;
  int n = blockIdx.x * 4 + (t >> 6);
  const float4* qrow = (const float4*)(qkv + (size_t)n * 768);
  float4 q4 = qrow[lane];
  int rs = rowstart[n], re = rowstart[n + 1];
  float m = -INFINITY, l = 0.f;
  float ax = 0.f, ay = 0.f, az = 0.f, aw = 0.f;
  for (int i = rs; i < re; ++i) {
    int e  = edgeids[i];
    int s  = src[e];
    int et = etype[e];
    const float* base = qkv + (size_t)s * 768;
    float4 ete4 = ((const float4*)(ete_s + et * 256))[lane];
    float4 k4 = ((const float4*)(base + 256))[lane];
    float4 v4 = ((const float4*)(base + 512))[lane];
    float p = (k4.x + ete4.x) * q4.x + (k4.y + ete4.y) * q4.y +
              (k4.z + ete4.z) * q4.z + (k4.w + ete4.w) * q4.w;
    p += __shfl_xor(p, 1);
    p += __shfl_xor(p, 2);
    p += __shfl_xor(p, 4);
    p += __shfl_xor(p, 8);
    float sc = p * 0.125f;                 // 1/sqrt(64)
    float mn = fmaxf(m, sc);
    float corr = __expf(m - mn);           // first iter: exp(-inf)=0
    float pe   = __expf(sc - mn);
    l = l * corr + pe;
    ax = ax * corr + pe * (v4.x + ete4.x);
    ay = ay * corr + pe * (v4.y + ete4.y);
    az = az * corr + pe * (v4.z + ete4.z);
    aw = aw * corr + pe * (v4.w + ete4.w);
    m = mn;
  }
  float inv = 1.f / (l + 1e-16f);
  float4 o;
  o.x = ax * inv; o.y = ay * inv; o.z = az * inv; o.w = aw * inv;
  o.x = o.x > 0.f ? o.x : expm1f(o.x);
  o.y = o.y > 0.f ? o.y : expm1f(o.y);
  o.z = o.z > 0.f ? o.z : expm1f(o.z);
  o.w = o.w > 0.f ? o.w : expm1f(o.w);
  ((float4*)(xout + (size_t)n * 256))[lane] = o;
}

// ---------------- global mean pool (batch is sorted) ----------------
__device__ inline int lower_bound_dev(const int* a, int n, int val) {
  int lo = 0, hi = n;
  while (lo < hi) {
    int mid = (lo + hi) >> 1;
    if (a[mid] < val) lo = mid + 1; else hi = mid;
  }
  return lo;
}

__global__ __launch_bounds__(256) void k_pool(const float* __restrict__ x,
                                              const int* __restrict__ batch,
                                              float* __restrict__ g) {
  int gr = blockIdx.x;
  int t = threadIdx.x;
  int s = lower_bound_dev(batch, N_NODES, gr);
  int e = lower_bound_dev(batch, N_NODES, gr + 1);
  float acc = 0.f;
  for (int n = s; n < e; ++n) acc += x[(size_t)n * 256 + t];
  float c = (e > s) ? (float)(e - s) : 1.f;
  g[gr * 256 + t] = acc / c;
}

// ---------------- GRU (h0=0, one step) + FC ----------------
__global__ __launch_bounds__(256) void k_gru_fc(
    const float* __restrict__ g, const float* __restrict__ W_ih,
    const float* __restrict__ b_ih, const float* __restrict__ b_hh,
    const float* __restrict__ W_fc, const float* __restrict__ b_fc,
    float* __restrict__ out) {
  __shared__ float gv[256];
  __shared__ float gates[192];
  __shared__ float h[64];
  int gr = blockIdx.x, t = threadIdx.x;
  gv[t] = g[gr * 256 + t];
  __syncthreads();
  if (t < 192) {
    const float* wr = W_ih + t * 256;
    float s = b_ih[t];
    for (int k = 0; k < 256; ++k) s = fmaf(gv[k], wr[k], s);
    gates[t] = s;
  }
  __syncthreads();
  if (t < 64) {
    // h0 = 0 => gh = b_hh
    float r  = 1.f / (1.f + expf(-(gates[t] + b_hh[t])));
    float z  = 1.f / (1.f + expf(-(gates[64 + t] + b_hh[64 + t])));
    float nn = tanhf(gates[128 + t] + r * b_hh[128 + t]);
    h[t] = (1.f - z) * nn;   // + z*h0 = 0
  }
  __syncthreads();
  if (t < 2) {
    const float* wr = W_fc + t * 64;
    float s = b_fc[t];
    for (int k = 0; k < 64; ++k) s = fmaf(h[k], wr[k], s);
    out[gr * 2 + t] = s;
  }
}

extern "C" void kernel_launch(void* const* d_in, const int* in_sizes, int n_in,
                              void* d_out, int out_size, void* d_ws, size_t ws_size,
                              hipStream_t stream) {
  const float* x     = (const float*)d_in[0];
  const int* edge_index = (const int*)d_in[1];   // [2,E]: row0=src, row1=dst
  const int* batch   = (const int*)d_in[2];
  const int* etype   = (const int*)d_in[3];
  const float* Wq    = (const float*)d_in[4];
  const float* bq    = (const float*)d_in[5];
  const float* Wk    = (const float*)d_in[6];
  const float* bk    = (const float*)d_in[7];
  const float* Wv    = (const float*)d_in[8];
  const float* bv    = (const float*)d_in[9];
  const float* Eemb  = (const float*)d_in[10];
  const float* W_ih  = (const float*)d_in[11];
  const float* b_ih  = (const float*)d_in[12];
  /* d_in[13] = W_hh, unused since h0 == 0 */
  const float* b_hh  = (const float*)d_in[14];
  const float* W_fc  = (const float*)d_in[15];
  const float* b_fc  = (const float*)d_in[16];
  float* out = (float*)d_out;

  const int* src = edge_index;
  const int* dst = edge_index + N_EDGES;

  // workspace layout (~124 MB)
  float* qkv   = (float*)d_ws;                       // N*768
  float* xbuf  = qkv + (size_t)N_NODES * 768;        // N*256
  float* gpool = xbuf + (size_t)N_NODES * 256;       // 64*256
  int* deg      = (int*)(gpool + NGRAPHS * 256);     // N
  int* rowstart = deg + N_NODES;                     // N+1
  int* cursor   = rowstart + N_NODES + 1;            // N
  int* edgeids  = cursor + N_NODES;                  // E

  hipMemsetAsync(deg, 0, N_NODES * sizeof(int), stream);
  k_count_deg<<<(N_EDGES + 255) / 256, 256, 0, stream>>>(dst, deg);
  k_scan<<<1, 1024, 0, stream>>>(deg, rowstart, cursor);
  k_scatter<<<(N_EDGES + 255) / 256, 256, 0, stream>>>(dst, cursor, edgeids);

  const float* xin = x;
  for (int l = 0; l < NLAYERS; ++l) {
    k_gemm_qkv<<<dim3((N_NODES + 127) / 128, 6), 256, 0, stream>>>(
        xin, Wq + (size_t)l * 65536, Wk + (size_t)l * 65536, Wv + (size_t)l * 65536,
        bq + l * 256, bk + l * 256, bv + l * 256, qkv);
    k_attn<<<N_NODES / 4, 256, 0, stream>>>(qkv, rowstart, edgeids, src, etype,
                                            Eemb + (size_t)l * NETYPES * 256, xbuf);
    xin = xbuf;
  }
  k_pool<<<NGRAPHS, 256, 0, stream>>>(xbuf, batch, gpool);
  k_gru_fc<<<NGRAPHS, 256, 0, stream>>>(gpool, W_ih, b_ih, b_hh, W_fc, b_fc, out);
}

// Round 2
// 781.586 us; speedup vs baseline: 1.3036x; 1.3036x over previous
//
#include <hip/hip_runtime.h>
#include <math.h>

#define N_NODES 30000
#define N_EDGES 240000
#define DMODEL 256
#define NETYPES 8
#define NGRAPHS 64
#define NLAYERS 3

typedef __attribute__((ext_vector_type(8))) short short8;
typedef __attribute__((ext_vector_type(4))) float f32x4;

// ---- bf16 split helpers (round-to-nearest-even) ----
__device__ __forceinline__ unsigned short f2bf(float f) {
  union { float f; unsigned u; } v; v.f = f;
  unsigned r = v.u + 0x7FFF + ((v.u >> 16) & 1);
  return (unsigned short)(r >> 16);
}
__device__ __forceinline__ float bf2f(unsigned short h) {
  union { unsigned u; float f; } v; v.u = ((unsigned)h) << 16;
  return v.f;
}

__device__ __forceinline__ void async_g2l(const unsigned short* g, unsigned short* l) {
  __builtin_amdgcn_global_load_lds(
      (const __attribute__((address_space(1))) void*)g,
      (__attribute__((address_space(3))) void*)l, 16, 0, 0);
}

// ---------------- CSR build (by destination node) ----------------
__global__ void k_count_deg(const int* __restrict__ dst, int* __restrict__ deg) {
  int e = blockIdx.x * blockDim.x + threadIdx.x;
  if (e < N_EDGES) atomicAdd(&deg[dst[e]], 1);
}

__global__ __launch_bounds__(1024) void k_scan(const int* __restrict__ deg,
                                               int* __restrict__ rowstart,
                                               int* __restrict__ cursor) {
  __shared__ int buf[1024];
  __shared__ int carry_s;
  int tid = threadIdx.x;
  if (tid == 0) carry_s = 0;
  __syncthreads();
  for (int base = 0; base < N_NODES; base += 1024) {
    int i = base + tid;
    int v = (i < N_NODES) ? deg[i] : 0;
    buf[tid] = v;
    __syncthreads();
    for (int off = 1; off < 1024; off <<= 1) {
      int t2 = (tid >= off) ? buf[tid - off] : 0;
      __syncthreads();
      buf[tid] += t2;
      __syncthreads();
    }
    int incl = buf[tid];
    int carry = carry_s;
    if (i < N_NODES) {
      rowstart[i] = carry + incl - v;
      cursor[i]   = carry + incl - v;
    }
    __syncthreads();
    if (tid == 1023) carry_s = carry + incl;
    __syncthreads();
  }
  if (tid == 0) rowstart[N_NODES] = carry_s;
}

__global__ void k_scatter(const int* __restrict__ dst, int* __restrict__ cursor,
                          int* __restrict__ edgeids) {
  int e = blockIdx.x * blockDim.x + threadIdx.x;
  if (e < N_EDGES) {
    int p = atomicAdd(&cursor[dst[e]], 1);
    edgeids[p] = e;
  }
}

// ---------------- weight transpose + bf16 hi/lo split (once per call) ----------
// Wt[l][n][k] (n in 0..767 over q|k|v) from Wq/Wk/Wv[l][k][col]
__global__ __launch_bounds__(256) void k_cvt_w(
    const float* __restrict__ Wq, const float* __restrict__ Wk, const float* __restrict__ Wv,
    unsigned short* __restrict__ wthi, unsigned short* __restrict__ wtlo) {
  int idx = blockIdx.x * 256 + threadIdx.x;     // 3*768*256 = 589824
  if (idx >= NLAYERS * 768 * 256) return;
  int k = idx & 255;
  int n = (idx >> 8) % 768;
  int l = idx / (768 * 256);
  int which = n >> 8, col = n & 255;
  const float* W = (which == 0) ? Wq : ((which == 1) ? Wk : Wv);
  float v = W[(size_t)l * 65536 + k * 256 + col];
  unsigned short h = f2bf(v);
  wthi[idx] = h;
  wtlo[idx] = f2bf(v - bf2f(h));
}

__global__ void k_cvt_b(const float* __restrict__ bq, const float* __restrict__ bk,
                        const float* __restrict__ bv, float* __restrict__ bcat) {
  int idx = blockIdx.x * 256 + threadIdx.x;     // 3*768
  if (idx >= NLAYERS * 768) return;
  int n = idx % 768, l = idx / 768;
  int which = n >> 8, col = n & 255;
  const float* b = (which == 0) ? bq : ((which == 1) ? bk : bv);
  bcat[idx] = b[l * 256 + col];
}

// ---------------- layer-0 activation split ----------------
__global__ void k_cvt_x(const float* __restrict__ x, unsigned short* __restrict__ xhi,
                        unsigned short* __restrict__ xlo) {
  int i = blockIdx.x * 256 + threadIdx.x;
  if (i < N_NODES * 256) {
    float v = x[i];
    unsigned short h = f2bf(v);
    xhi[i] = h;
    xlo[i] = f2bf(v - bf2f(h));
  }
}

// ---------------- split-bf16 MFMA GEMM: qkv[N,768] = (hi+lo)A @ (hi+lo)Wt^T + bcat ----
// 128x128 tile, BK=32, 4 waves each 64x64 (4x4 frags of 16x16x32), 3-term split.
__global__ __launch_bounds__(256) void k_gemm_mfma(
    const unsigned short* __restrict__ Ahi, const unsigned short* __restrict__ Alo,
    const unsigned short* __restrict__ Bhi, const unsigned short* __restrict__ Blo,
    const float* __restrict__ bcat, float* __restrict__ C) {
  __shared__ unsigned short smem[4 * 128 * 32];
  unsigned short* sAhi = smem;
  unsigned short* sAlo = smem + 4096;
  unsigned short* sBhi = smem + 8192;
  unsigned short* sBlo = smem + 12288;

  int tid = threadIdx.x;
  int lane = tid & 63, wave = tid >> 6;
  int row0 = blockIdx.x * 128;
  int n0 = blockIdx.y * 128;
  int wm = (wave >> 1) * 64, wn = (wave & 1) * 64;
  int quad = lane >> 4, l16 = lane & 15;
  int chunk = lane & 3;
  int srow = wave * 32 + (lane >> 2);

  f32x4 acc[4][4];
#pragma unroll
  for (int i = 0; i < 4; ++i)
#pragma unroll
    for (int j = 0; j < 4; ++j) acc[i][j] = (f32x4)(0.f);

  for (int k0 = 0; k0 < 256; k0 += 32) {
#pragma unroll
    for (int j = 0; j < 2; ++j) {
      int r = srow + j * 16;
      int ldsoff = wave * 1024 + j * 512;          // elems
      int garA = row0 + r; if (garA >= N_NODES) garA = N_NODES - 1;
      size_t aoff = (size_t)garA * 256 + k0 + chunk * 8;
      async_g2l(Ahi + aoff, sAhi + ldsoff);
      async_g2l(Alo + aoff, sAlo + ldsoff);
      size_t boff = (size_t)(n0 + r) * 256 + k0 + chunk * 8;
      async_g2l(Bhi + boff, sBhi + ldsoff);
      async_g2l(Blo + boff, sBlo + ldsoff);
    }
    __syncthreads();
    short8 ah[4], al[4], bh[4], bl[4];
#pragma unroll
    for (int i = 0; i < 4; ++i) {
      int off = (wm + i * 16 + l16) * 32 + quad * 8;
      ah[i] = *(const short8*)(sAhi + off);
      al[i] = *(const short8*)(sAlo + off);
    }
#pragma unroll
    for (int j = 0; j < 4; ++j) {
      int off = (wn + j * 16 + l16) * 32 + quad * 8;
      bh[j] = *(const short8*)(sBhi + off);
      bl[j] = *(const short8*)(sBlo + off);
    }
#pragma unroll
    for (int i = 0; i < 4; ++i)
#pragma unroll
      for (int j = 0; j < 4; ++j) {
        acc[i][j] = __builtin_amdgcn_mfma_f32_16x16x32_bf16(ah[i], bh[j], acc[i][j], 0, 0, 0);
        acc[i][j] = __builtin_amdgcn_mfma_f32_16x16x32_bf16(ah[i], bl[j], acc[i][j], 0, 0, 0);
        acc[i][j] = __builtin_amdgcn_mfma_f32_16x16x32_bf16(al[i], bh[j], acc[i][j], 0, 0, 0);
      }
    __syncthreads();
  }

  float bj[4];
#pragma unroll
  for (int j = 0; j < 4; ++j) bj[j] = bcat[n0 + wn + j * 16 + l16];
#pragma unroll
  for (int i = 0; i < 4; ++i) {
    int rowb = row0 + wm + i * 16 + quad * 4;
#pragma unroll
    for (int r = 0; r < 4; ++r) {
      int grow = rowb + r;
      if (grow < N_NODES) {
        float* cp = C + (size_t)grow * 768 + n0 + wn + l16;
#pragma unroll
        for (int j = 0; j < 4; ++j) cp[j * 16] = acc[i][j][r] + bj[j];
      }
    }
  }
}

// ---------------- per-dst-node edge attention, online softmax, no atomics ----------
__global__ __launch_bounds__(256) void k_attn(
    const float* __restrict__ qkv, const int* __restrict__ rowstart,
    const int* __restrict__ edgeids, const int* __restrict__ src,
    const int* __restrict__ etype, const float* __restrict__ Eemb_l,
    unsigned short* __restrict__ xhi, unsigned short* __restrict__ xlo) {
  __shared__ float ete_s[NETYPES * 256];
  int t = threadIdx.x;
#pragma unroll
  for (int i = 0; i < NETYPES; ++i) ete_s[i * 256 + t] = Eemb_l[i * 256 + t];
  __syncthreads();
  int lane = t & 63;
  int n = blockIdx.x * 4 + (t >> 6);
  const float4* qrow = (const float4*)(qkv + (size_t)n * 768);
  float4 q4 = qrow[lane];
  int rs = rowstart[n], re = rowstart[n + 1];
  float m = -INFINITY, l = 0.f;
  float ax = 0.f, ay = 0.f, az = 0.f, aw = 0.f;
  for (int i = rs; i < re; ++i) {
    int e  = edgeids[i];
    int s  = src[e];
    int et = etype[e];
    const float* base = qkv + (size_t)s * 768;
    float4 ete4 = ((const float4*)(ete_s + et * 256))[lane];
    float4 k4 = ((const float4*)(base + 256))[lane];
    float4 v4 = ((const float4*)(base + 512))[lane];
    float p = (k4.x + ete4.x) * q4.x + (k4.y + ete4.y) * q4.y +
              (k4.z + ete4.z) * q4.z + (k4.w + ete4.w) * q4.w;
    p += __shfl_xor(p, 1);
    p += __shfl_xor(p, 2);
    p += __shfl_xor(p, 4);
    p += __shfl_xor(p, 8);
    float sc = p * 0.125f;
    float mn = fmaxf(m, sc);
    float corr = __expf(m - mn);
    float pe   = __expf(sc - mn);
    l = l * corr + pe;
    ax = ax * corr + pe * (v4.x + ete4.x);
    ay = ay * corr + pe * (v4.y + ete4.y);
    az = az * corr + pe * (v4.z + ete4.z);
    aw = aw * corr + pe * (v4.w + ete4.w);
    m = mn;
  }
  float inv = 1.f / (l + 1e-16f);
  float4 o;
  o.x = ax * inv; o.y = ay * inv; o.z = az * inv; o.w = aw * inv;
  o.x = o.x > 0.f ? o.x : expm1f(o.x);
  o.y = o.y > 0.f ? o.y : expm1f(o.y);
  o.z = o.z > 0.f ? o.z : expm1f(o.z);
  o.w = o.w > 0.f ? o.w : expm1f(o.w);
  // split into bf16 hi/lo for next layer's MFMA GEMM (and final pool)
  unsigned short h0 = f2bf(o.x), h1 = f2bf(o.y), h2 = f2bf(o.z), h3 = f2bf(o.w);
  ushort4 hv, lv;
  hv.x = h0; hv.y = h1; hv.z = h2; hv.w = h3;
  lv.x = f2bf(o.x - bf2f(h0)); lv.y = f2bf(o.y - bf2f(h1));
  lv.z = f2bf(o.z - bf2f(h2)); lv.w = f2bf(o.w - bf2f(h3));
  size_t base_o = (size_t)n * 256 + lane * 4;
  *(ushort4*)(xhi + base_o) = hv;
  *(ushort4*)(xlo + base_o) = lv;
}

// ---------------- global mean pool (batch is sorted), x = hi+lo ----------------
__device__ inline int lower_bound_dev(const int* a, int n, int val) {
  int lo = 0, hi = n;
  while (lo < hi) {
    int mid = (lo + hi) >> 1;
    if (a[mid] < val) lo = mid + 1; else hi = mid;
  }
  return lo;
}

__global__ __launch_bounds__(256) void k_pool(const unsigned short* __restrict__ xhi,
                                              const unsigned short* __restrict__ xlo,
                                              const int* __restrict__ batch,
                                              float* __restrict__ g) {
  int gr = blockIdx.x;
  int t = threadIdx.x;
  int s = lower_bound_dev(batch, N_NODES, gr);
  int e = lower_bound_dev(batch, N_NODES, gr + 1);
  float acc = 0.f;
  for (int n = s; n < e; ++n) {
    size_t idx = (size_t)n * 256 + t;
    acc += bf2f(xhi[idx]) + bf2f(xlo[idx]);
  }
  float c = (e > s) ? (float)(e - s) : 1.f;
  g[gr * 256 + t] = acc / c;
}

// ---------------- GRU (h0=0, one step) + FC ----------------
__global__ __launch_bounds__(256) void k_gru_fc(
    const float* __restrict__ g, const float* __restrict__ W_ih,
    const float* __restrict__ b_ih, const float* __restrict__ b_hh,
    const float* __restrict__ W_fc, const float* __restrict__ b_fc,
    float* __restrict__ out) {
  __shared__ float gv[256];
  __shared__ float gates[192];
  __shared__ float h[64];
  int gr = blockIdx.x, t = threadIdx.x;
  gv[t] = g[gr * 256 + t];
  __syncthreads();
  if (t < 192) {
    const float* wr = W_ih + t * 256;
    float s = b_ih[t];
    for (int k = 0; k < 256; ++k) s = fmaf(gv[k], wr[k], s);
    gates[t] = s;
  }
  __syncthreads();
  if (t < 64) {
    float r  = 1.f / (1.f + expf(-(gates[t] + b_hh[t])));
    float z  = 1.f / (1.f + expf(-(gates[64 + t] + b_hh[64 + t])));
    float nn = tanhf(gates[128 + t] + r * b_hh[128 + t]);
    h[t] = (1.f - z) * nn;
  }
  __syncthreads();
  if (t < 2) {
    const float* wr = W_fc + t * 64;
    float s = b_fc[t];
    for (int k = 0; k < 64; ++k) s = fmaf(h[k], wr[k], s);
    out[gr * 2 + t] = s;
  }
}

extern "C" void kernel_launch(void* const* d_in, const int* in_sizes, int n_in,
                              void* d_out, int out_size, void* d_ws, size_t ws_size,
                              hipStream_t stream) {
  const float* x     = (const float*)d_in[0];
  const int* edge_index = (const int*)d_in[1];
  const int* batch   = (const int*)d_in[2];
  const int* etype   = (const int*)d_in[3];
  const float* Wq    = (const float*)d_in[4];
  const float* bq    = (const float*)d_in[5];
  const float* Wk    = (const float*)d_in[6];
  const float* bk    = (const float*)d_in[7];
  const float* Wv    = (const float*)d_in[8];
  const float* bv    = (const float*)d_in[9];
  const float* Eemb  = (const float*)d_in[10];
  const float* W_ih  = (const float*)d_in[11];
  const float* b_ih  = (const float*)d_in[12];
  const float* b_hh  = (const float*)d_in[14];
  const float* W_fc  = (const float*)d_in[15];
  const float* b_fc  = (const float*)d_in[16];
  float* out = (float*)d_out;

  const int* src = edge_index;
  const int* dst = edge_index + N_EDGES;

  // workspace layout (~127 MB)
  float* qkv   = (float*)d_ws;                           // N*768 f32
  float* gpool = qkv + (size_t)N_NODES * 768;            // 64*256
  float* bcat  = gpool + NGRAPHS * 256;                  // 3*768
  unsigned short* xhi  = (unsigned short*)(bcat + NLAYERS * 768);  // N*256 bf16
  unsigned short* xlo  = xhi + (size_t)N_NODES * 256;
  unsigned short* wthi = xlo + (size_t)N_NODES * 256;    // 3*768*256
  unsigned short* wtlo = wthi + (size_t)NLAYERS * 768 * 256;
  int* deg      = (int*)(wtlo + (size_t)NLAYERS * 768 * 256);
  int* rowstart = deg + N_NODES;
  int* cursor   = rowstart + N_NODES + 1;
  int* edgeids  = cursor + N_NODES;

  hipMemsetAsync(deg, 0, N_NODES * sizeof(int), stream);
  k_count_deg<<<(N_EDGES + 255) / 256, 256, 0, stream>>>(dst, deg);
  k_scan<<<1, 1024, 0, stream>>>(deg, rowstart, cursor);
  k_scatter<<<(N_EDGES + 255) / 256, 256, 0, stream>>>(dst, cursor, edgeids);

  k_cvt_w<<<(NLAYERS * 768 * 256 + 255) / 256, 256, 0, stream>>>(Wq, Wk, Wv, wthi, wtlo);
  k_cvt_b<<<(NLAYERS * 768 + 255) / 256, 256, 0, stream>>>(bq, bk, bv, bcat);
  k_cvt_x<<<(N_NODES * 256 + 255) / 256, 256, 0, stream>>>(x, xhi, xlo);

  for (int l = 0; l < NLAYERS; ++l) {
    k_gemm_mfma<<<dim3((N_NODES + 127) / 128, 6), 256, 0, stream>>>(
        xhi, xlo,
        wthi + (size_t)l * 768 * 256, wtlo + (size_t)l * 768 * 256,
        bcat + l * 768, qkv);
    k_attn<<<N_NODES / 4, 256, 0, stream>>>(qkv, rowstart, edgeids, src, etype,
                                            Eemb + (size_t)l * NETYPES * 256, xhi, xlo);
  }
  k_pool<<<NGRAPHS, 256, 0, stream>>>(xhi, xlo, batch, gpool);
  k_gru_fc<<<NGRAPHS, 256, 0, stream>>>(gpool, W_ih, b_ih, b_hh, W_fc, b_fc, out);
}

// Round 3
// 554.101 us; speedup vs baseline: 1.8388x; 1.4105x over previous
//
#include <hip/hip_runtime.h>
#include <math.h>

#define N_NODES 30000
#define N_EDGES 240000
#define DMODEL 256
#define NETYPES 8
#define NGRAPHS 64
#define NLAYERS 3

typedef __attribute__((ext_vector_type(8))) short short8;
typedef __attribute__((ext_vector_type(4))) float f32x4;

// ---- bf16 split helpers (round-to-nearest-even) ----
__device__ __forceinline__ unsigned short f2bf(float f) {
  union { float f; unsigned u; } v; v.f = f;
  unsigned r = v.u + 0x7FFF + ((v.u >> 16) & 1);
  return (unsigned short)(r >> 16);
}
__device__ __forceinline__ float bf2f(unsigned short h) {
  union { unsigned u; float f; } v; v.u = ((unsigned)h) << 16;
  return v.f;
}

__device__ __forceinline__ void async_g2l(const unsigned short* g, unsigned short* l) {
  __builtin_amdgcn_global_load_lds(
      (const __attribute__((address_space(1))) void*)g,
      (__attribute__((address_space(3))) void*)l, 16, 0, 0);
}

// ---------------- CSR build (by destination node) ----------------
__global__ void k_count_deg(const int* __restrict__ dst, int* __restrict__ deg) {
  int e = blockIdx.x * blockDim.x + threadIdx.x;
  if (e < N_EDGES) atomicAdd(&deg[dst[e]], 1);
}

// single block, 1024 threads, 30 elems/thread; wave shuffle-scan + 16-wave LDS scan
__global__ __launch_bounds__(1024) void k_scan(const int* __restrict__ deg,
                                               int* __restrict__ rowstart,
                                               int* __restrict__ cursor) {
  const int C = 30;  // 1024*30 = 30720 >= N_NODES
  int tid = threadIdx.x;
  int base = tid * C;
  int vals[C];
  int sum = 0;
#pragma unroll
  for (int j = 0; j < C; ++j) {
    int idx = base + j;
    int v = (idx < N_NODES) ? deg[idx] : 0;
    vals[j] = sum;           // local exclusive prefix
    sum += v;
  }
  int lane = tid & 63, wv = tid >> 6;
  int s = sum;
#pragma unroll
  for (int off = 1; off < 64; off <<= 1) {
    int t2 = __shfl_up(s, off);
    if (lane >= off) s += t2;
  }
  __shared__ int wsum[16];
  if (lane == 63) wsum[wv] = s;
  __syncthreads();
  if (tid == 0) {
    int a = 0;
#pragma unroll
    for (int i = 0; i < 16; ++i) { int t2 = wsum[i]; wsum[i] = a; a += t2; }
    rowstart[N_NODES] = a;
  }
  __syncthreads();
  int texcl = wsum[wv] + (s - sum);   // exclusive prefix of this thread's chunk
#pragma unroll
  for (int j = 0; j < C; ++j) {
    int idx = base + j;
    if (idx < N_NODES) {
      int p = texcl + vals[j];
      rowstart[idx] = p;
      cursor[idx]   = p;
    }
  }
}

// CSR-ordered packed edge meta: packed[p] = src*8 + etype
__global__ void k_scatter(const int* __restrict__ src, const int* __restrict__ dst,
                          const int* __restrict__ etype, int* __restrict__ cursor,
                          int* __restrict__ packed) {
  int e = blockIdx.x * blockDim.x + threadIdx.x;
  if (e < N_EDGES) {
    int p = atomicAdd(&cursor[dst[e]], 1);
    packed[p] = src[e] * NETYPES + etype[e];
  }
}

// ---------------- weight transpose + bf16 hi/lo split ----------
__global__ __launch_bounds__(256) void k_cvt_w(
    const float* __restrict__ Wq, const float* __restrict__ Wk, const float* __restrict__ Wv,
    unsigned short* __restrict__ wthi, unsigned short* __restrict__ wtlo) {
  int idx = blockIdx.x * 256 + threadIdx.x;
  if (idx >= NLAYERS * 768 * 256) return;
  int k = idx & 255;
  int n = (idx >> 8) % 768;
  int l = idx / (768 * 256);
  int which = n >> 8, col = n & 255;
  const float* W = (which == 0) ? Wq : ((which == 1) ? Wk : Wv);
  float v = W[(size_t)l * 65536 + k * 256 + col];
  unsigned short h = f2bf(v);
  wthi[idx] = h;
  wtlo[idx] = f2bf(v - bf2f(h));
}

__global__ void k_cvt_b(const float* __restrict__ bq, const float* __restrict__ bk,
                        const float* __restrict__ bv, float* __restrict__ bcat) {
  int idx = blockIdx.x * 256 + threadIdx.x;
  if (idx >= NLAYERS * 768) return;
  int n = idx % 768, l = idx / 768;
  int which = n >> 8, col = n & 255;
  const float* b = (which == 0) ? bq : ((which == 1) ? bk : bv);
  bcat[idx] = b[l * 256 + col];
}

__global__ void k_cvt_x(const float* __restrict__ x, unsigned short* __restrict__ xhi,
                        unsigned short* __restrict__ xlo) {
  int i = blockIdx.x * 256 + threadIdx.x;
  if (i < N_NODES * 256) {
    float v = x[i];
    unsigned short h = f2bf(v);
    xhi[i] = h;
    xlo[i] = f2bf(v - bf2f(h));
  }
}

// ---------------- split-bf16 MFMA GEMM ----------------
// q cols (0..255) -> qbuf fp32 [N,256]; k|v cols (256..767) -> kv bf16 [N,512]
__global__ __launch_bounds__(256) void k_gemm_mfma(
    const unsigned short* __restrict__ Ahi, const unsigned short* __restrict__ Alo,
    const unsigned short* __restrict__ Bhi, const unsigned short* __restrict__ Blo,
    const float* __restrict__ bcat, float* __restrict__ qbuf,
    unsigned short* __restrict__ kv) {
  __shared__ unsigned short smem[4 * 128 * 32];
  unsigned short* sAhi = smem;
  unsigned short* sAlo = smem + 4096;
  unsigned short* sBhi = smem + 8192;
  unsigned short* sBlo = smem + 12288;

  int tid = threadIdx.x;
  int lane = tid & 63, wave = tid >> 6;
  int row0 = blockIdx.x * 128;
  int n0 = blockIdx.y * 128;
  int wm = (wave >> 1) * 64, wn = (wave & 1) * 64;
  int quad = lane >> 4, l16 = lane & 15;
  int chunk = lane & 3;
  int srow = wave * 32 + (lane >> 2);

  f32x4 acc[4][4];
#pragma unroll
  for (int i = 0; i < 4; ++i)
#pragma unroll
    for (int j = 0; j < 4; ++j) acc[i][j] = (f32x4)(0.f);

  for (int k0 = 0; k0 < 256; k0 += 32) {
#pragma unroll
    for (int j = 0; j < 2; ++j) {
      int r = srow + j * 16;
      int ldsoff = wave * 1024 + j * 512;
      int garA = row0 + r; if (garA >= N_NODES) garA = N_NODES - 1;
      size_t aoff = (size_t)garA * 256 + k0 + chunk * 8;
      async_g2l(Ahi + aoff, sAhi + ldsoff);
      async_g2l(Alo + aoff, sAlo + ldsoff);
      size_t boff = (size_t)(n0 + r) * 256 + k0 + chunk * 8;
      async_g2l(Bhi + boff, sBhi + ldsoff);
      async_g2l(Blo + boff, sBlo + ldsoff);
    }
    __syncthreads();
    short8 ah[4], al[4], bh[4], bl[4];
#pragma unroll
    for (int i = 0; i < 4; ++i) {
      int off = (wm + i * 16 + l16) * 32 + quad * 8;
      ah[i] = *(const short8*)(sAhi + off);
      al[i] = *(const short8*)(sAlo + off);
    }
#pragma unroll
    for (int j = 0; j < 4; ++j) {
      int off = (wn + j * 16 + l16) * 32 + quad * 8;
      bh[j] = *(const short8*)(sBhi + off);
      bl[j] = *(const short8*)(sBlo + off);
    }
#pragma unroll
    for (int i = 0; i < 4; ++i)
#pragma unroll
      for (int j = 0; j < 4; ++j) {
        acc[i][j] = __builtin_amdgcn_mfma_f32_16x16x32_bf16(ah[i], bh[j], acc[i][j], 0, 0, 0);
        acc[i][j] = __builtin_amdgcn_mfma_f32_16x16x32_bf16(ah[i], bl[j], acc[i][j], 0, 0, 0);
        acc[i][j] = __builtin_amdgcn_mfma_f32_16x16x32_bf16(al[i], bh[j], acc[i][j], 0, 0, 0);
      }
    __syncthreads();
  }

  float bj[4];
#pragma unroll
  for (int j = 0; j < 4; ++j) bj[j] = bcat[n0 + wn + j * 16 + l16];
  bool isq = (n0 < 256);
#pragma unroll
  for (int i = 0; i < 4; ++i) {
    int rowb = row0 + wm + i * 16 + quad * 4;
#pragma unroll
    for (int r = 0; r < 4; ++r) {
      int grow = rowb + r;
      if (grow < N_NODES) {
        if (isq) {
          float* cp = qbuf + (size_t)grow * 256 + n0 + wn + l16;
#pragma unroll
          for (int j = 0; j < 4; ++j) cp[j * 16] = acc[i][j][r] + bj[j];
        } else {
          unsigned short* cp = kv + (size_t)grow * 512 + (n0 - 256) + wn + l16;
#pragma unroll
          for (int j = 0; j < 4; ++j) cp[j * 16] = f2bf(acc[i][j][r] + bj[j]);
        }
      }
    }
  }
}

// ---------------- per-dst-node edge attention, online softmax ----------
__global__ __launch_bounds__(256) void k_attn(
    const float* __restrict__ qbuf, const unsigned short* __restrict__ kv,
    const int* __restrict__ rowstart, const int* __restrict__ packed,
    const float* __restrict__ Eemb_l,
    unsigned short* __restrict__ xhi, unsigned short* __restrict__ xlo) {
  __shared__ float ete_s[NETYPES * 256];
  int t = threadIdx.x;
#pragma unroll
  for (int i = 0; i < NETYPES; ++i) ete_s[i * 256 + t] = Eemb_l[i * 256 + t];
  __syncthreads();
  int lane = t & 63;
  int n = blockIdx.x * 4 + (t >> 6);
  float4 q4 = ((const float4*)(qbuf + (size_t)n * 256))[lane];
  int rs = rowstart[n], re = rowstart[n + 1];
  float m = -INFINITY, l = 0.f;
  float ax = 0.f, ay = 0.f, az = 0.f, aw = 0.f;
  for (int i = rs; i < re; ++i) {
    int pk = packed[i];                       // wave-uniform
    const unsigned short* base = kv + (size_t)(pk >> 3) * 512;
    float4 ete4 = ((const float4*)(ete_s + (pk & 7) * 256))[lane];
    ushort4 kh = ((const ushort4*)base)[lane];
    ushort4 vh = ((const ushort4*)(base + 256))[lane];
    float p = (bf2f(kh.x) + ete4.x) * q4.x + (bf2f(kh.y) + ete4.y) * q4.y +
              (bf2f(kh.z) + ete4.z) * q4.z + (bf2f(kh.w) + ete4.w) * q4.w;
    p += __shfl_xor(p, 1);
    p += __shfl_xor(p, 2);
    p += __shfl_xor(p, 4);
    p += __shfl_xor(p, 8);
    float sc = p * 0.125f;
    float mn = fmaxf(m, sc);
    float corr = __expf(m - mn);
    float pe   = __expf(sc - mn);
    l = l * corr + pe;
    ax = ax * corr + pe * (bf2f(vh.x) + ete4.x);
    ay = ay * corr + pe * (bf2f(vh.y) + ete4.y);
    az = az * corr + pe * (bf2f(vh.z) + ete4.z);
    aw = aw * corr + pe * (bf2f(vh.w) + ete4.w);
    m = mn;
  }
  float inv = 1.f / (l + 1e-16f);
  float4 o;
  o.x = ax * inv; o.y = ay * inv; o.z = az * inv; o.w = aw * inv;
  o.x = o.x > 0.f ? o.x : expm1f(o.x);
  o.y = o.y > 0.f ? o.y : expm1f(o.y);
  o.z = o.z > 0.f ? o.z : expm1f(o.z);
  o.w = o.w > 0.f ? o.w : expm1f(o.w);
  unsigned short h0 = f2bf(o.x), h1 = f2bf(o.y), h2 = f2bf(o.z), h3 = f2bf(o.w);
  ushort4 hv, lv;
  hv.x = h0; hv.y = h1; hv.z = h2; hv.w = h3;
  lv.x = f2bf(o.x - bf2f(h0)); lv.y = f2bf(o.y - bf2f(h1));
  lv.z = f2bf(o.z - bf2f(h2)); lv.w = f2bf(o.w - bf2f(h3));
  size_t base_o = (size_t)n * 256 + lane * 4;
  *(ushort4*)(xhi + base_o) = hv;
  *(ushort4*)(xlo + base_o) = lv;
}

// ---------------- parallel mean pool, stage 1: per-chunk partial sums ----------
__global__ __launch_bounds__(256) void k_pool_partial(
    const unsigned short* __restrict__ xhi, const unsigned short* __restrict__ xlo,
    const int* __restrict__ batch, float* __restrict__ gacc) {
  int t = threadIdx.x;
  int base = blockIdx.x * 128;
  int end = base + 128; if (end > N_NODES) end = N_NODES;
  __shared__ int bsh[128];
  if (t < 128 && base + t < N_NODES) bsh[t] = batch[base + t];
  __syncthreads();
  float acc = 0.f;
  int cur = bsh[0];
  for (int n = base; n < end; ++n) {
    int g = bsh[n - base];
    if (g != cur) {
      atomicAdd(&gacc[cur * 256 + t], acc);
      acc = 0.f; cur = g;
    }
    size_t idx = (size_t)n * 256 + t;
    acc += bf2f(xhi[idx]) + bf2f(xlo[idx]);
  }
  atomicAdd(&gacc[cur * 256 + t], acc);
}

// ---------------- GRU (h0=0) + FC, with mean divide ----------------
__device__ inline int lower_bound_dev(const int* a, int n, int val) {
  int lo = 0, hi = n;
  while (lo < hi) {
    int mid = (lo + hi) >> 1;
    if (a[mid] < val) lo = mid + 1; else hi = mid;
  }
  return lo;
}

__global__ __launch_bounds__(256) void k_gru_fc(
    const float* __restrict__ gacc, const int* __restrict__ batch,
    const float* __restrict__ W_ih, const float* __restrict__ b_ih,
    const float* __restrict__ b_hh, const float* __restrict__ W_fc,
    const float* __restrict__ b_fc, float* __restrict__ out) {
  __shared__ float gv[256];
  __shared__ float gates[192];
  __shared__ float h[64];
  int gr = blockIdx.x, t = threadIdx.x;
  int s0 = lower_bound_dev(batch, N_NODES, gr);
  int e0 = lower_bound_dev(batch, N_NODES, gr + 1);
  float c = (e0 > s0) ? (float)(e0 - s0) : 1.f;
  gv[t] = gacc[gr * 256 + t] / c;
  __syncthreads();
  if (t < 192) {
    const float* wr = W_ih + t * 256;
    float s = b_ih[t];
    for (int k = 0; k < 256; ++k) s = fmaf(gv[k], wr[k], s);
    gates[t] = s;
  }
  __syncthreads();
  if (t < 64) {
    float r  = 1.f / (1.f + expf(-(gates[t] + b_hh[t])));
    float z  = 1.f / (1.f + expf(-(gates[64 + t] + b_hh[64 + t])));
    float nn = tanhf(gates[128 + t] + r * b_hh[128 + t]);
    h[t] = (1.f - z) * nn;
  }
  __syncthreads();
  if (t < 2) {
    const float* wr = W_fc + t * 64;
    float s = b_fc[t];
    for (int k = 0; k < 64; ++k) s = fmaf(h[k], wr[k], s);
    out[gr * 2 + t] = s;
  }
}

extern "C" void kernel_launch(void* const* d_in, const int* in_sizes, int n_in,
                              void* d_out, int out_size, void* d_ws, size_t ws_size,
                              hipStream_t stream) {
  const float* x     = (const float*)d_in[0];
  const int* edge_index = (const int*)d_in[1];
  const int* batch   = (const int*)d_in[2];
  const int* etype   = (const int*)d_in[3];
  const float* Wq    = (const float*)d_in[4];
  const float* bq    = (const float*)d_in[5];
  const float* Wk    = (const float*)d_in[6];
  const float* bk    = (const float*)d_in[7];
  const float* Wv    = (const float*)d_in[8];
  const float* bv    = (const float*)d_in[9];
  const float* Eemb  = (const float*)d_in[10];
  const float* W_ih  = (const float*)d_in[11];
  const float* b_ih  = (const float*)d_in[12];
  const float* b_hh  = (const float*)d_in[14];
  const float* W_fc  = (const float*)d_in[15];
  const float* b_fc  = (const float*)d_in[16];
  float* out = (float*)d_out;

  const int* src = edge_index;
  const int* dst = edge_index + N_EDGES;

  // workspace layout (~97 MB)
  float* qbuf  = (float*)d_ws;                             // N*256 f32
  float* gacc  = qbuf + (size_t)N_NODES * 256;             // 64*256
  float* bcat  = gacc + NGRAPHS * 256;                     // 3*768
  unsigned short* kv   = (unsigned short*)(bcat + NLAYERS * 768);  // N*512 bf16
  unsigned short* xhi  = kv + (size_t)N_NODES * 512;       // N*256
  unsigned short* xlo  = xhi + (size_t)N_NODES * 256;
  unsigned short* wthi = xlo + (size_t)N_NODES * 256;      // 3*768*256
  unsigned short* wtlo = wthi + (size_t)NLAYERS * 768 * 256;
  int* deg      = (int*)(wtlo + (size_t)NLAYERS * 768 * 256);
  int* rowstart = deg + N_NODES;
  int* cursor   = rowstart + N_NODES + 1;
  int* packed   = cursor + N_NODES;

  hipMemsetAsync(deg, 0, N_NODES * sizeof(int), stream);
  hipMemsetAsync(gacc, 0, NGRAPHS * 256 * sizeof(float), stream);
  k_count_deg<<<(N_EDGES + 255) / 256, 256, 0, stream>>>(dst, deg);
  k_scan<<<1, 1024, 0, stream>>>(deg, rowstart, cursor);
  k_scatter<<<(N_EDGES + 255) / 256, 256, 0, stream>>>(src, dst, etype, cursor, packed);

  k_cvt_w<<<(NLAYERS * 768 * 256 + 255) / 256, 256, 0, stream>>>(Wq, Wk, Wv, wthi, wtlo);
  k_cvt_b<<<(NLAYERS * 768 + 255) / 256, 256, 0, stream>>>(bq, bk, bv, bcat);
  k_cvt_x<<<(N_NODES * 256 + 255) / 256, 256, 0, stream>>>(x, xhi, xlo);

  for (int l = 0; l < NLAYERS; ++l) {
    k_gemm_mfma<<<dim3((N_NODES + 127) / 128, 6), 256, 0, stream>>>(
        xhi, xlo,
        wthi + (size_t)l * 768 * 256, wtlo + (size_t)l * 768 * 256,
        bcat + l * 768, qbuf, kv);
    k_attn<<<N_NODES / 4, 256, 0, stream>>>(qbuf, kv, rowstart, packed,
                                            Eemb + (size_t)l * NETYPES * 256, xhi, xlo);
  }
  k_pool_partial<<<(N_NODES + 127) / 128, 256, 0, stream>>>(xhi, xlo, batch, gacc);
  k_gru_fc<<<NGRAPHS, 256, 0, stream>>>(gacc, batch, W_ih, b_ih, b_hh, W_fc, b_fc, out);
}

// Round 4
// 510.729 us; speedup vs baseline: 1.9949x; 1.0849x over previous
//
#include <hip/hip_runtime.h>
#include <math.h>

#define N_NODES 30000
#define N_EDGES 240000
#define DMODEL 256
#define NETYPES 8
#define NGRAPHS 64
#define NLAYERS 3

typedef __attribute__((ext_vector_type(8))) short short8;
typedef __attribute__((ext_vector_type(4))) float f32x4;

// ---- bf16 split helpers (round-to-nearest-even) ----
__device__ __forceinline__ unsigned short f2bf(float f) {
  union { float f; unsigned u; } v; v.f = f;
  unsigned r = v.u + 0x7FFF + ((v.u >> 16) & 1);
  return (unsigned short)(r >> 16);
}
__device__ __forceinline__ float bf2f(unsigned short h) {
  union { unsigned u; float f; } v; v.u = ((unsigned)h) << 16;
  return v.f;
}

__device__ __forceinline__ void async_g2l(const unsigned short* g, unsigned short* l) {
  __builtin_amdgcn_global_load_lds(
      (const __attribute__((address_space(1))) void*)g,
      (__attribute__((address_space(3))) void*)l, 16, 0, 0);
}

// ---------------- CSR build (by destination node) ----------------
__global__ void k_count_deg(const int* __restrict__ dst, int* __restrict__ deg) {
  int e = blockIdx.x * blockDim.x + threadIdx.x;
  if (e < N_EDGES) atomicAdd(&deg[dst[e]], 1);
}

__global__ __launch_bounds__(1024) void k_scan(const int* __restrict__ deg,
                                               int* __restrict__ rowstart,
                                               int* __restrict__ cursor) {
  const int C = 30;
  int tid = threadIdx.x;
  int base = tid * C;
  int vals[C];
  int sum = 0;
#pragma unroll
  for (int j = 0; j < C; ++j) {
    int idx = base + j;
    int v = (idx < N_NODES) ? deg[idx] : 0;
    vals[j] = sum;
    sum += v;
  }
  int lane = tid & 63, wv = tid >> 6;
  int s = sum;
#pragma unroll
  for (int off = 1; off < 64; off <<= 1) {
    int t2 = __shfl_up(s, off);
    if (lane >= off) s += t2;
  }
  __shared__ int wsum[16];
  if (lane == 63) wsum[wv] = s;
  __syncthreads();
  if (tid == 0) {
    int a = 0;
#pragma unroll
    for (int i = 0; i < 16; ++i) { int t2 = wsum[i]; wsum[i] = a; a += t2; }
    rowstart[N_NODES] = a;
  }
  __syncthreads();
  int texcl = wsum[wv] + (s - sum);
#pragma unroll
  for (int j = 0; j < C; ++j) {
    int idx = base + j;
    if (idx < N_NODES) {
      int p = texcl + vals[j];
      rowstart[idx] = p;
      cursor[idx]   = p;
    }
  }
}

__global__ void k_scatter(const int* __restrict__ src, const int* __restrict__ dst,
                          const int* __restrict__ etype, int* __restrict__ cursor,
                          int* __restrict__ packed) {
  int e = blockIdx.x * blockDim.x + threadIdx.x;
  if (e < N_EDGES) {
    int p = atomicAdd(&cursor[dst[e]], 1);
    packed[p] = src[e] * NETYPES + etype[e];
  }
}

// ---------------- weight transpose (coalesced, LDS tile), bf16 hi only ----------
__global__ __launch_bounds__(256) void k_cvt_w(
    const float* __restrict__ Wq, const float* __restrict__ Wk, const float* __restrict__ Wv,
    unsigned short* __restrict__ wthi) {
  __shared__ float tile[32][33];
  int k0 = blockIdx.x * 32;          // 0..224
  int n0g = blockIdx.y * 32;         // 0..736
  int l = blockIdx.z;
  int which = n0g >> 8;
  int col0 = n0g & 255;
  const float* W = (which == 0) ? Wq : ((which == 1) ? Wk : Wv);
  int c = threadIdx.x & 31, r = threadIdx.x >> 5;
#pragma unroll
  for (int rr = 0; rr < 4; ++rr) {
    int kk = r + rr * 8;
    tile[kk][c] = W[(size_t)l * 65536 + (size_t)(k0 + kk) * 256 + col0 + c];
  }
  __syncthreads();
  int kk = threadIdx.x & 31, nn0 = threadIdx.x >> 5;
#pragma unroll
  for (int rr = 0; rr < 4; ++rr) {
    int nn = nn0 + rr * 8;
    wthi[((size_t)l * 768 + n0g + nn) * 256 + k0 + kk] = f2bf(tile[kk][nn]);
  }
}

__global__ void k_cvt_b(const float* __restrict__ bq, const float* __restrict__ bk,
                        const float* __restrict__ bv, float* __restrict__ bcat) {
  int idx = blockIdx.x * 256 + threadIdx.x;
  if (idx >= NLAYERS * 768) return;
  int n = idx % 768, l = idx / 768;
  int which = n >> 8, col = n & 255;
  const float* b = (which == 0) ? bq : ((which == 1) ? bk : bv);
  bcat[idx] = b[l * 256 + col];
}

__global__ void k_cvt_x(const float* __restrict__ x, unsigned short* __restrict__ xhi,
                        unsigned short* __restrict__ xlo) {
  int i = blockIdx.x * 256 + threadIdx.x;
  if (i < N_NODES * 256) {
    float v = x[i];
    unsigned short h = f2bf(v);
    xhi[i] = h;
    xlo[i] = f2bf(v - bf2f(h));
  }
}

// ---------------- split-bf16 MFMA GEMM, 2-term (Ahi*Bhi + Alo*Bhi) ----------
// linear grid: row = bx/6, col-block = bx%6 (6 readers of each A-tile adjacent)
__global__ __launch_bounds__(256) void k_gemm_mfma(
    const unsigned short* __restrict__ Ahi, const unsigned short* __restrict__ Alo,
    const unsigned short* __restrict__ Bhi,
    const float* __restrict__ bcat, float* __restrict__ qbuf,
    unsigned short* __restrict__ kv) {
  __shared__ unsigned short smem[3 * 4096];
  unsigned short* sAhi = smem;
  unsigned short* sAlo = smem + 4096;
  unsigned short* sBhi = smem + 8192;

  int tid = threadIdx.x;
  int lane = tid & 63, wave = tid >> 6;
  int bx = blockIdx.x;
  int row0 = (bx / 6) * 128;
  int n0 = (bx % 6) * 128;
  int wm = (wave >> 1) * 64, wn = (wave & 1) * 64;
  int quad = lane >> 4, l16 = lane & 15;
  int chunk = lane & 3;
  int srow = wave * 32 + (lane >> 2);

  f32x4 acc[4][4];
#pragma unroll
  for (int i = 0; i < 4; ++i)
#pragma unroll
    for (int j = 0; j < 4; ++j) acc[i][j] = (f32x4)(0.f);

  for (int k0 = 0; k0 < 256; k0 += 32) {
#pragma unroll
    for (int j = 0; j < 2; ++j) {
      int r = srow + j * 16;
      int ldsoff = wave * 1024 + j * 512;
      int garA = row0 + r; if (garA >= N_NODES) garA = N_NODES - 1;
      size_t aoff = (size_t)garA * 256 + k0 + chunk * 8;
      async_g2l(Ahi + aoff, sAhi + ldsoff);
      async_g2l(Alo + aoff, sAlo + ldsoff);
      size_t boff = (size_t)(n0 + r) * 256 + k0 + chunk * 8;
      async_g2l(Bhi + boff, sBhi + ldsoff);
    }
    __syncthreads();
    short8 ah[4], al[4], bh[4];
#pragma unroll
    for (int i = 0; i < 4; ++i) {
      int off = (wm + i * 16 + l16) * 32 + quad * 8;
      ah[i] = *(const short8*)(sAhi + off);
      al[i] = *(const short8*)(sAlo + off);
    }
#pragma unroll
    for (int j = 0; j < 4; ++j) {
      int off = (wn + j * 16 + l16) * 32 + quad * 8;
      bh[j] = *(const short8*)(sBhi + off);
    }
#pragma unroll
    for (int i = 0; i < 4; ++i)
#pragma unroll
      for (int j = 0; j < 4; ++j) {
        acc[i][j] = __builtin_amdgcn_mfma_f32_16x16x32_bf16(ah[i], bh[j], acc[i][j], 0, 0, 0);
        acc[i][j] = __builtin_amdgcn_mfma_f32_16x16x32_bf16(al[i], bh[j], acc[i][j], 0, 0, 0);
      }
    __syncthreads();
  }

  float bj[4];
#pragma unroll
  for (int j = 0; j < 4; ++j) bj[j] = bcat[n0 + wn + j * 16 + l16];
  bool isq = (n0 < 256);
#pragma unroll
  for (int i = 0; i < 4; ++i) {
    int rowb = row0 + wm + i * 16 + quad * 4;
#pragma unroll
    for (int r = 0; r < 4; ++r) {
      int grow = rowb + r;
      if (grow < N_NODES) {
        if (isq) {
          float* cp = qbuf + (size_t)grow * 256 + n0 + wn + l16;
#pragma unroll
          for (int j = 0; j < 4; ++j) cp[j * 16] = acc[i][j][r] + bj[j];
        } else {
          unsigned short* cp = kv + (size_t)grow * 512 + (n0 - 256) + wn + l16;
#pragma unroll
          for (int j = 0; j < 4; ++j) cp[j * 16] = f2bf(acc[i][j][r] + bj[j]);
        }
      }
    }
  }
}

// ---------------- per-dst-node edge attention, max-free softmax, 2x unroll ----------
__global__ __launch_bounds__(256) void k_attn(
    const float* __restrict__ qbuf, const unsigned short* __restrict__ kv,
    const int* __restrict__ rowstart, const int* __restrict__ packed,
    const float* __restrict__ Eemb_l,
    unsigned short* __restrict__ xhi, unsigned short* __restrict__ xlo) {
  __shared__ float ete_s[NETYPES * 256];
  int t = threadIdx.x;
#pragma unroll
  for (int i = 0; i < NETYPES; ++i) ete_s[i * 256 + t] = Eemb_l[i * 256 + t];
  __syncthreads();
  int lane = t & 63;
  int n = blockIdx.x * 4 + (t >> 6);
  float4 q4 = ((const float4*)(qbuf + (size_t)n * 256))[lane];
  int rs = rowstart[n], re = rowstart[n + 1];
  float l1 = 0.f, ax1 = 0.f, ay1 = 0.f, az1 = 0.f, aw1 = 0.f;
  float l2 = 0.f, ax2 = 0.f, ay2 = 0.f, az2 = 0.f, aw2 = 0.f;
  int i = rs;
  for (; i + 2 <= re; i += 2) {
    int pkA = packed[i], pkB = packed[i + 1];
    const unsigned short* baseA = kv + (size_t)(pkA >> 3) * 512;
    const unsigned short* baseB = kv + (size_t)(pkB >> 3) * 512;
    ushort4 kA = ((const ushort4*)baseA)[lane];
    ushort4 vA = ((const ushort4*)(baseA + 256))[lane];
    ushort4 kB = ((const ushort4*)baseB)[lane];
    ushort4 vB = ((const ushort4*)(baseB + 256))[lane];
    float4 eA = ((const float4*)(ete_s + (pkA & 7) * 256))[lane];
    float4 eB = ((const float4*)(ete_s + (pkB & 7) * 256))[lane];
    float pA = (bf2f(kA.x) + eA.x) * q4.x + (bf2f(kA.y) + eA.y) * q4.y +
               (bf2f(kA.z) + eA.z) * q4.z + (bf2f(kA.w) + eA.w) * q4.w;
    float pB = (bf2f(kB.x) + eB.x) * q4.x + (bf2f(kB.y) + eB.y) * q4.y +
               (bf2f(kB.z) + eB.z) * q4.z + (bf2f(kB.w) + eB.w) * q4.w;
    pA += __shfl_xor(pA, 1); pB += __shfl_xor(pB, 1);
    pA += __shfl_xor(pA, 2); pB += __shfl_xor(pB, 2);
    pA += __shfl_xor(pA, 4); pB += __shfl_xor(pB, 4);
    pA += __shfl_xor(pA, 8); pB += __shfl_xor(pB, 8);
    float e1 = __expf(pA * 0.125f);
    float e2 = __expf(pB * 0.125f);
    l1 += e1; l2 += e2;
    ax1 = fmaf(e1, bf2f(vA.x) + eA.x, ax1);
    ay1 = fmaf(e1, bf2f(vA.y) + eA.y, ay1);
    az1 = fmaf(e1, bf2f(vA.z) + eA.z, az1);
    aw1 = fmaf(e1, bf2f(vA.w) + eA.w, aw1);
    ax2 = fmaf(e2, bf2f(vB.x) + eB.x, ax2);
    ay2 = fmaf(e2, bf2f(vB.y) + eB.y, ay2);
    az2 = fmaf(e2, bf2f(vB.z) + eB.z, az2);
    aw2 = fmaf(e2, bf2f(vB.w) + eB.w, aw2);
  }
  if (i < re) {
    int pk = packed[i];
    const unsigned short* base = kv + (size_t)(pk >> 3) * 512;
    ushort4 kh = ((const ushort4*)base)[lane];
    ushort4 vh = ((const ushort4*)(base + 256))[lane];
    float4 e4 = ((const float4*)(ete_s + (pk & 7) * 256))[lane];
    float p = (bf2f(kh.x) + e4.x) * q4.x + (bf2f(kh.y) + e4.y) * q4.y +
              (bf2f(kh.z) + e4.z) * q4.z + (bf2f(kh.w) + e4.w) * q4.w;
    p += __shfl_xor(p, 1);
    p += __shfl_xor(p, 2);
    p += __shfl_xor(p, 4);
    p += __shfl_xor(p, 8);
    float e1 = __expf(p * 0.125f);
    l1 += e1;
    ax1 = fmaf(e1, bf2f(vh.x) + e4.x, ax1);
    ay1 = fmaf(e1, bf2f(vh.y) + e4.y, ay1);
    az1 = fmaf(e1, bf2f(vh.z) + e4.z, az1);
    aw1 = fmaf(e1, bf2f(vh.w) + e4.w, aw1);
  }
  float l = l1 + l2;
  float inv = 1.f / (l + 1e-16f);
  float4 o;
  o.x = (ax1 + ax2) * inv; o.y = (ay1 + ay2) * inv;
  o.z = (az1 + az2) * inv; o.w = (aw1 + aw2) * inv;
  o.x = o.x > 0.f ? o.x : expm1f(o.x);
  o.y = o.y > 0.f ? o.y : expm1f(o.y);
  o.z = o.z > 0.f ? o.z : expm1f(o.z);
  o.w = o.w > 0.f ? o.w : expm1f(o.w);
  unsigned short h0 = f2bf(o.x), h1 = f2bf(o.y), h2 = f2bf(o.z), h3 = f2bf(o.w);
  ushort4 hv, lv;
  hv.x = h0; hv.y = h1; hv.z = h2; hv.w = h3;
  lv.x = f2bf(o.x - bf2f(h0)); lv.y = f2bf(o.y - bf2f(h1));
  lv.z = f2bf(o.z - bf2f(h2)); lv.w = f2bf(o.w - bf2f(h3));
  size_t base_o = (size_t)n * 256 + lane * 4;
  *(ushort4*)(xhi + base_o) = hv;
  *(ushort4*)(xlo + base_o) = lv;
}

// ---------------- parallel mean pool, stage 1 ----------------
__global__ __launch_bounds__(256) void k_pool_partial(
    const unsigned short* __restrict__ xhi, const unsigned short* __restrict__ xlo,
    const int* __restrict__ batch, float* __restrict__ gacc) {
  int t = threadIdx.x;
  int base = blockIdx.x * 128;
  int end = base + 128; if (end > N_NODES) end = N_NODES;
  __shared__ int bsh[128];
  if (t < 128 && base + t < N_NODES) bsh[t] = batch[base + t];
  __syncthreads();
  float acc = 0.f;
  int cur = bsh[0];
  for (int n = base; n < end; ++n) {
    int g = bsh[n - base];
    if (g != cur) {
      atomicAdd(&gacc[cur * 256 + t], acc);
      acc = 0.f; cur = g;
    }
    size_t idx = (size_t)n * 256 + t;
    acc += bf2f(xhi[idx]) + bf2f(xlo[idx]);
  }
  atomicAdd(&gacc[cur * 256 + t], acc);
}

// ---------------- GRU (h0=0) + FC ----------------
__device__ inline int lower_bound_dev(const int* a, int n, int val) {
  int lo = 0, hi = n;
  while (lo < hi) {
    int mid = (lo + hi) >> 1;
    if (a[mid] < val) lo = mid + 1; else hi = mid;
  }
  return lo;
}

__global__ __launch_bounds__(256) void k_gru_fc(
    const float* __restrict__ gacc, const int* __restrict__ batch,
    const float* __restrict__ W_ih, const float* __restrict__ b_ih,
    const float* __restrict__ b_hh, const float* __restrict__ W_fc,
    const float* __restrict__ b_fc, float* __restrict__ out) {
  __shared__ float gv[256];
  __shared__ float gates[192];
  __shared__ float h[64];
  int gr = blockIdx.x, t = threadIdx.x;
  int s0 = lower_bound_dev(batch, N_NODES, gr);
  int e0 = lower_bound_dev(batch, N_NODES, gr + 1);
  float c = (e0 > s0) ? (float)(e0 - s0) : 1.f;
  gv[t] = gacc[gr * 256 + t] / c;
  __syncthreads();
  if (t < 192) {
    const float* wr = W_ih + t * 256;
    float s = b_ih[t];
    for (int k = 0; k < 256; ++k) s = fmaf(gv[k], wr[k], s);
    gates[t] = s;
  }
  __syncthreads();
  if (t < 64) {
    float r  = 1.f / (1.f + expf(-(gates[t] + b_hh[t])));
    float z  = 1.f / (1.f + expf(-(gates[64 + t] + b_hh[64 + t])));
    float nn = tanhf(gates[128 + t] + r * b_hh[128 + t]);
    h[t] = (1.f - z) * nn;
  }
  __syncthreads();
  if (t < 2) {
    const float* wr = W_fc + t * 64;
    float s = b_fc[t];
    for (int k = 0; k < 64; ++k) s = fmaf(h[k], wr[k], s);
    out[gr * 2 + t] = s;
  }
}

extern "C" void kernel_launch(void* const* d_in, const int* in_sizes, int n_in,
                              void* d_out, int out_size, void* d_ws, size_t ws_size,
                              hipStream_t stream) {
  const float* x     = (const float*)d_in[0];
  const int* edge_index = (const int*)d_in[1];
  const int* batch   = (const int*)d_in[2];
  const int* etype   = (const int*)d_in[3];
  const float* Wq    = (const float*)d_in[4];
  const float* bq    = (const float*)d_in[5];
  const float* Wk    = (const float*)d_in[6];
  const float* bk    = (const float*)d_in[7];
  const float* Wv    = (const float*)d_in[8];
  const float* bv    = (const float*)d_in[9];
  const float* Eemb  = (const float*)d_in[10];
  const float* W_ih  = (const float*)d_in[11];
  const float* b_ih  = (const float*)d_in[12];
  const float* b_hh  = (const float*)d_in[14];
  const float* W_fc  = (const float*)d_in[15];
  const float* b_fc  = (const float*)d_in[16];
  float* out = (float*)d_out;

  const int* src = edge_index;
  const int* dst = edge_index + N_EDGES;

  float* qbuf  = (float*)d_ws;                             // N*256 f32
  float* gacc  = qbuf + (size_t)N_NODES * 256;             // 64*256
  float* bcat  = gacc + NGRAPHS * 256;                     // 3*768
  unsigned short* kv   = (unsigned short*)(bcat + NLAYERS * 768);  // N*512 bf16
  unsigned short* xhi  = kv + (size_t)N_NODES * 512;       // N*256
  unsigned short* xlo  = xhi + (size_t)N_NODES * 256;
  unsigned short* wthi = xlo + (size_t)N_NODES * 256;      // 3*768*256
  int* deg      = (int*)(wthi + (size_t)NLAYERS * 768 * 256);
  int* rowstart = deg + N_NODES;
  int* cursor   = rowstart + N_NODES + 1;
  int* packed   = cursor + N_NODES;

  hipMemsetAsync(deg, 0, N_NODES * sizeof(int), stream);
  hipMemsetAsync(gacc, 0, NGRAPHS * 256 * sizeof(float), stream);
  k_count_deg<<<(N_EDGES + 255) / 256, 256, 0, stream>>>(dst, deg);
  k_scan<<<1, 1024, 0, stream>>>(deg, rowstart, cursor);
  k_scatter<<<(N_EDGES + 255) / 256, 256, 0, stream>>>(src, dst, etype, cursor, packed);

  k_cvt_w<<<dim3(8, 24, 3), 256, 0, stream>>>(Wq, Wk, Wv, wthi);
  k_cvt_b<<<(NLAYERS * 768 + 255) / 256, 256, 0, stream>>>(bq, bk, bv, bcat);
  k_cvt_x<<<(N_NODES * 256 + 255) / 256, 256, 0, stream>>>(x, xhi, xlo);

  for (int l = 0; l < NLAYERS; ++l) {
    k_gemm_mfma<<<235 * 6, 256, 0, stream>>>(
        xhi, xlo, wthi + (size_t)l * 768 * 256,
        bcat + l * 768, qbuf, kv);
    k_attn<<<N_NODES / 4, 256, 0, stream>>>(qbuf, kv, rowstart, packed,
                                            Eemb + (size_t)l * NETYPES * 256, xhi, xlo);
  }
  k_pool_partial<<<(N_NODES + 127) / 128, 256, 0, stream>>>(xhi, xlo, batch, gacc);
  k_gru_fc<<<NGRAPHS, 256, 0, stream>>>(gacc, batch, W_ih, b_ih, b_hh, W_fc, b_fc, out);
}